// Round 4
// baseline (1175.154 us; speedup 1.0000x reference)
//
#include <hip/hip_runtime.h>
#include <hip/hip_bf16.h>

typedef __bf16 bf16;
typedef bf16 bf16x8 __attribute__((ext_vector_type(8)));
typedef float f32x4 __attribute__((ext_vector_type(4)));

__device__ __forceinline__ float sigm(float x) { return 1.0f / (1.0f + __expf(-x)); }
__device__ __forceinline__ float tanh_f(float x) { return 2.0f / (1.0f + __expf(-2.0f * x)) - 1.0f; }

// ---------------------------------------------------------------------------
// fp32 -> bf16 conversion of x + 13 weight matrices into one packed ws area.
// ---------------------------------------------------------------------------
struct Cvt13 { const float* src[13]; unsigned gcnt[13]; };  // gcnt = elems/8

__global__ __launch_bounds__(256) void cvt_all(Cvt13 a, bf16* __restrict__ dst,
                                               unsigned total_g) {
    unsigned g = blockIdx.x * 256 + threadIdx.x;
    if (g >= total_g) return;
    unsigned s = 0, base = 0;
    while (g >= base + a.gcnt[s]) { base += a.gcnt[s]; ++s; }
    const float* sp = a.src[s] + (size_t)(g - base) * 8;
    float4 v0 = ((const float4*)sp)[0];
    float4 v1 = ((const float4*)sp)[1];
    bf16x8 o;
    o[0] = (bf16)v0.x; o[1] = (bf16)v0.y; o[2] = (bf16)v0.z; o[3] = (bf16)v0.w;
    o[4] = (bf16)v1.x; o[5] = (bf16)v1.y; o[6] = (bf16)v1.z; o[7] = (bf16)v1.w;
    *(bf16x8*)(dst + (size_t)g * 8) = o;
}

// ---------------------------------------------------------------------------
// GEMM: C[M,N] = act(A[M,K] @ W[N,K]^T + bias[N]).  BM=64, BN=128, BK=32.
// ---------------------------------------------------------------------------
template <int ACT, typename OutT>
__global__ __launch_bounds__(256) void gemm_bt(
    const bf16* __restrict__ A, const bf16* __restrict__ W,
    const float* __restrict__ bias, OutT* __restrict__ C,
    int M, int N, int K)
{
    __shared__ __attribute__((aligned(16))) bf16 sA[64 * 32];   // 4 KB
    __shared__ __attribute__((aligned(16))) bf16 sB[128 * 32];  // 8 KB
    const int t = threadIdx.x;
    const int lane = t & 63;
    const int w = t >> 6;
    const int wm = w >> 1, wn = w & 1;
    const int quad = lane >> 4, l16 = lane & 15;
    const int m0 = blockIdx.y * 64, n0 = blockIdx.x * 128;

    f32x4 acc[2][4] = {};

    const int nk = K >> 5;
    for (int kc = 0; kc < nk; ++kc) {
        const int k0 = kc << 5;
        if (kc) __syncthreads();
        {
            int row = t >> 2, kof = (t & 3) << 3;
            bf16x8 v = *(const bf16x8*)(A + (size_t)(m0 + row) * K + k0 + kof);
            *(bf16x8*)(sA + row * 32 + kof) = v;
        }
        for (int i = 0; i < 2; ++i) {
            int gi = (i << 8) + t;
            int row = gi >> 2, kof = (gi & 3) << 3;
            bf16x8 v = *(const bf16x8*)(W + (size_t)(n0 + row) * K + k0 + kof);
            *(bf16x8*)(sB + row * 32 + kof) = v;
        }
        __syncthreads();
        bf16x8 af[2], bfr[4];
        for (int mi = 0; mi < 2; ++mi)
            af[mi] = *(const bf16x8*)(sA + ((wm * 32 + mi * 16 + l16) * 32 + quad * 8));
        for (int ni = 0; ni < 4; ++ni)
            bfr[ni] = *(const bf16x8*)(sB + ((wn * 64 + ni * 16 + l16) * 32 + quad * 8));
        for (int mi = 0; mi < 2; ++mi)
            for (int ni = 0; ni < 4; ++ni)
                acc[mi][ni] = __builtin_amdgcn_mfma_f32_16x16x32_bf16(
                    af[mi], bfr[ni], acc[mi][ni], 0, 0, 0);
    }
    for (int mi = 0; mi < 2; ++mi) {
        for (int ni = 0; ni < 4; ++ni) {
            int gn = n0 + wn * 64 + ni * 16 + l16;
            float bv = bias[gn];
            for (int r = 0; r < 4; ++r) {
                int gm = m0 + wm * 32 + mi * 16 + quad * 4 + r;
                float v = acc[mi][ni][r] + bv;
                if (ACT) v = v >= 0.f ? v : 0.2f * v;
                C[(size_t)gm * N + gn] = (OutT)v;
            }
        }
    }
}

// ---------------------------------------------------------------------------
// Fused LSTM step: gates = h@Whh^T + xt@Wih^T + (bih+bhh); c,h update.
// ---------------------------------------------------------------------------
__global__ __launch_bounds__(256) void lstm_step(
    const bf16* __restrict__ hin, const bf16* __restrict__ xt,
    const bf16* __restrict__ Whh, const bf16* __restrict__ Wih,
    const float* __restrict__ bih, const float* __restrict__ bhh,
    float* __restrict__ cbuf, bf16* __restrict__ hout)
{
    __shared__ __attribute__((aligned(16))) bf16 sA[128 * 32];  // 8 KB
    __shared__ __attribute__((aligned(16))) bf16 sB[128 * 32];  // 8 KB
    const int t = threadIdx.x;
    const int lane = t & 63;
    const int w = t >> 6;
    const int wm = w >> 1, wn = w & 1;
    const int quad = lane >> 4, l16 = lane & 15;
    const int m0 = blockIdx.y * 128;
    const int j0 = blockIdx.x * 32;

    f32x4 acc[4][4] = {};  // [mi][gate]

    for (int kc = 0; kc < 16; ++kc) {
        const int k0 = kc << 5;
        if (kc) __syncthreads();
        for (int i = 0; i < 2; ++i) {
            int gi = (i << 8) + t;
            int row = gi >> 2, kof = (gi & 3) << 3;
            bf16x8 v = *(const bf16x8*)(hin + (size_t)(m0 + row) * 512 + k0 + kof);
            *(bf16x8*)(sA + row * 32 + kof) = v;
        }
        for (int i = 0; i < 2; ++i) {
            int gi = (i << 8) + t;
            int row = gi >> 2, kof = (gi & 3) << 3;
            int wr = ((row >> 5) << 9) + j0 + (row & 31);  // gate*512 + j0 + jj
            bf16x8 v = *(const bf16x8*)(Whh + (size_t)wr * 512 + k0 + kof);
            *(bf16x8*)(sB + row * 32 + kof) = v;
        }
        __syncthreads();
        bf16x8 af[4], bfr[4];
        for (int mi = 0; mi < 4; ++mi)
            af[mi] = *(const bf16x8*)(sA + ((wm * 64 + mi * 16 + l16) * 32 + quad * 8));
        for (int g = 0; g < 4; ++g)
            bfr[g] = *(const bf16x8*)(sB + ((g * 32 + wn * 16 + l16) * 32 + quad * 8));
        for (int mi = 0; mi < 4; ++mi)
            for (int g = 0; g < 4; ++g)
                acc[mi][g] = __builtin_amdgcn_mfma_f32_16x16x32_bf16(
                    af[mi], bfr[g], acc[mi][g], 0, 0, 0);
    }

    // xt tail as a standard K=32 step with zero-padded LDS (k 16..31 = 0)
    __syncthreads();
    {
        bf16x8 z = {};
        for (int i = 0; i < 2; ++i) {
            int idx = ((i << 8) + t) << 3;
            *(bf16x8*)(sA + idx) = z;
            *(bf16x8*)(sB + idx) = z;
        }
    }
    __syncthreads();
    {
        int row = t >> 1, half = t & 1;
        *(bf16x8*)(sA + row * 32 + half * 8) =
            *(const bf16x8*)(xt + (size_t)(m0 + row) * 16 + half * 8);
        int wr = ((row >> 5) << 9) + j0 + (row & 31);
        *(bf16x8*)(sB + row * 32 + half * 8) =
            *(const bf16x8*)(Wih + (size_t)wr * 16 + half * 8);
    }
    __syncthreads();
    {
        bf16x8 af[4], bfr[4];
        for (int mi = 0; mi < 4; ++mi)
            af[mi] = *(const bf16x8*)(sA + ((wm * 64 + mi * 16 + l16) * 32 + quad * 8));
        for (int g = 0; g < 4; ++g)
            bfr[g] = *(const bf16x8*)(sB + ((g * 32 + wn * 16 + l16) * 32 + quad * 8));
        for (int mi = 0; mi < 4; ++mi)
            for (int g = 0; g < 4; ++g)
                acc[mi][g] = __builtin_amdgcn_mfma_f32_16x16x32_bf16(
                    af[mi], bfr[g], acc[mi][g], 0, 0, 0);
    }

    // epilogue: gate nonlinearities + c/h update (c kept fp32 across steps)
    const int j = j0 + wn * 16 + l16;
    float bsum[4];
    for (int g = 0; g < 4; ++g)
        bsum[g] = bih[(g << 9) + j] + bhh[(g << 9) + j];
    for (int mi = 0; mi < 4; ++mi) {
        for (int r = 0; r < 4; ++r) {
            int gm = m0 + wm * 64 + mi * 16 + quad * 4 + r;
            float i_ = sigm(acc[mi][0][r] + bsum[0]);
            float f_ = sigm(acc[mi][1][r] + bsum[1]);
            float g_ = tanh_f(acc[mi][2][r] + bsum[2]);
            float o_ = sigm(acc[mi][3][r] + bsum[3]);
            size_t idx = (size_t)gm * 512 + j;
            float cn = f_ * cbuf[idx] + i_ * g_;
            cbuf[idx] = cn;
            hout[idx] = (bf16)(o_ * tanh_f(cn));
        }
    }
}

// ---------------------------------------------------------------------------
// Head: out = [softmax(p[:15]), sigmoid(p[15])], p = A[M,512]@W[16,512]^T + b.
// Writes bf16 xt (LSTM feedback) and fp32 outp (final output, fp32 per ref).
// ---------------------------------------------------------------------------
__global__ __launch_bounds__(256) void head_gemm(
    const bf16* __restrict__ A, const bf16* __restrict__ W16,
    const float* __restrict__ bias, bf16* __restrict__ xt,
    float* __restrict__ outp, int ostride)
{
    __shared__ __attribute__((aligned(16))) bf16 sA[16 * 512];
    __shared__ __attribute__((aligned(16))) bf16 sW[16 * 520];
    const int t = threadIdx.x;
    const int m0 = blockIdx.x * 16;
    for (int i = 0; i < 4; ++i) {
        int c = (i << 8) + t;
        int row = c >> 6, kof = (c & 63) << 3;
        *(bf16x8*)(sA + row * 512 + kof) =
            *(const bf16x8*)(A + (size_t)(m0 + row) * 512 + kof);
    }
    for (int i = 0; i < 4; ++i) {
        int c = (i << 8) + t;
        int row = c >> 6, kof = (c & 63) << 3;
        *(bf16x8*)(sW + row * 520 + kof) =
            *(const bf16x8*)(W16 + (size_t)row * 512 + kof);
    }
    __syncthreads();
    const int rl = t >> 4, n = t & 15;
    const bf16* ap = sA + rl * 512;
    const bf16* wp = sW + n * 520;
    float acc = 0.f;
    for (int k = 0; k < 512; k += 8) {
        bf16x8 a8 = *(const bf16x8*)(ap + k);
        bf16x8 w8 = *(const bf16x8*)(wp + k);
        for (int jj = 0; jj < 8; ++jj) acc += (float)a8[jj] * (float)w8[jj];
    }
    float p = acc + bias[n];
    float vmax = (n == 15) ? -3.0e38f : p;
    for (int m = 8; m; m >>= 1) vmax = fmaxf(vmax, __shfl_xor(vmax, m));
    float e = (n == 15) ? 0.f : __expf(p - vmax);
    float s = e;
    for (int m = 8; m; m >>= 1) s += __shfl_xor(s, m);
    float res = (n == 15) ? sigm(p) : e / s;
    int gr = m0 + rl;
    xt[(size_t)gr * 16 + n] = (bf16)res;
    if (outp) outp[(size_t)gr * ostride + n] = res;   // fp32 output
}

// ---------------------------------------------------------------------------
extern "C" void kernel_launch(void* const* d_in, const int* in_sizes, int n_in,
                              void* d_out, int out_size, void* d_ws, size_t ws_size,
                              hipStream_t stream) {
    // inputs fp32; biases consumed directly as fp32; OUTPUT fp32
    const float* xf   = (const float*)d_in[0];
    const float* W1f  = (const float*)d_in[1];  const float* b1  = (const float*)d_in[2];
    const float* W2f  = (const float*)d_in[3];  const float* b2  = (const float*)d_in[4];
    const float* W3f  = (const float*)d_in[5];  const float* b3  = (const float*)d_in[6];
    const float* Wh1f = (const float*)d_in[7];  const float* bh1 = (const float*)d_in[8];
    const float* Wh2f = (const float*)d_in[9];  const float* bh2 = (const float*)d_in[10];
    const float* Wc1f = (const float*)d_in[11]; const float* bc1 = (const float*)d_in[12];
    const float* Wc2f = (const float*)d_in[13]; const float* bc2 = (const float*)d_in[14];
    const float* Wx1f = (const float*)d_in[15]; const float* bx1 = (const float*)d_in[16];
    const float* Wx2f = (const float*)d_in[17]; const float* bx2 = (const float*)d_in[18];
    const float* Wihf = (const float*)d_in[19]; const float* bih = (const float*)d_in[20];
    const float* Whhf = (const float*)d_in[21]; const float* bhh = (const float*)d_in[22];
    const float* Wpf  = (const float*)d_in[23]; const float* bp  = (const float*)d_in[24];
    float* out = (float*)d_out;
    char* ws = (char*)d_ws;

    bf16*  bufA = (bf16*)(ws + 0);            // 4 MB  (z1 / z3)
    bf16*  bufB = (bf16*)(ws + (4u  << 20));  // 4 MB  (mids; later h ping buf)
    bf16*  h0b  = (bf16*)(ws + (8u  << 20));  // 4 MB
    float* cb   = (float*)(ws + (12u << 20)); // 8 MB
    bf16*  xtb  = (bf16*)(ws + (20u << 20));  // 128 KB
    bf16*  cvt  = (bf16*)(ws + (21u << 20));  // ~7.05 MB of bf16 weights
    bf16*  h1b  = bufB;                       // alias: bufB free after head(x0)

    const unsigned Ns[13] = {
        4096u * 128u, 512u * 128u, 512u * 512u, 512u * 512u, 512u * 512u,
        512u * 512u, 512u * 512u, 512u * 512u, 512u * 512u, 16u * 512u,
        2048u * 16u, 2048u * 512u, 16u * 512u
    };
    const float* srcs[13] = { xf, W1f, W2f, W3f, Wh1f, Wh2f, Wc1f, Wc2f,
                              Wx1f, Wx2f, Wihf, Whhf, Wpf };
    Cvt13 ca;
    unsigned off[14]; off[0] = 0;
    for (int i = 0; i < 13; ++i) {
        ca.src[i] = srcs[i];
        ca.gcnt[i] = Ns[i] >> 3;
        off[i + 1] = off[i] + Ns[i];
    }
    unsigned total_g = off[13] >> 3;
    cvt_all<<<dim3((total_g + 255) / 256), dim3(256), 0, stream>>>(ca, cvt, total_g);

    const bf16* xb   = cvt + off[0];
    const bf16* W1b  = cvt + off[1];
    const bf16* W2b  = cvt + off[2];
    const bf16* W3b  = cvt + off[3];
    const bf16* Wh1b = cvt + off[4];
    const bf16* Wh2b = cvt + off[5];
    const bf16* Wc1b = cvt + off[6];
    const bf16* Wc2b = cvt + off[7];
    const bf16* Wx1b = cvt + off[8];
    const bf16* Wx2b = cvt + off[9];
    const bf16* Wihb = cvt + off[10];
    const bf16* Whhb = cvt + off[11];
    const bf16* Wpb  = cvt + off[12];

    dim3 blk(256);
    dim3 gg(4, 64);  // N/128 x M/64
    gemm_bt<1, bf16 ><<<gg, blk, 0, stream>>>(xb,   W1b,  b1,  bufA, 4096, 512, 128);
    gemm_bt<1, bf16 ><<<gg, blk, 0, stream>>>(bufA, W2b,  b2,  bufB, 4096, 512, 512);
    gemm_bt<1, bf16 ><<<gg, blk, 0, stream>>>(bufB, W3b,  b3,  bufA, 4096, 512, 512); // z3
    gemm_bt<1, bf16 ><<<gg, blk, 0, stream>>>(bufA, Wh1b, bh1, bufB, 4096, 512, 512);
    gemm_bt<0, bf16 ><<<gg, blk, 0, stream>>>(bufB, Wh2b, bh2, h0b,  4096, 512, 512);
    gemm_bt<1, bf16 ><<<gg, blk, 0, stream>>>(bufA, Wc1b, bc1, bufB, 4096, 512, 512);
    gemm_bt<0, float><<<gg, blk, 0, stream>>>(bufB, Wc2b, bc2, cb,   4096, 512, 512);
    gemm_bt<1, bf16 ><<<gg, blk, 0, stream>>>(bufA, Wx1b, bx1, bufB, 4096, 512, 512);
    head_gemm<<<dim3(256), blk, 0, stream>>>(bufB, Wx2b, bx2, xtb, (float*)nullptr, 0);

    bf16* hb[2] = { h0b, h1b };
    for (int t = 0; t < 32; ++t) {
        const bf16* hp = hb[t & 1];
        bf16* hn = hb[(t + 1) & 1];
        lstm_step<<<dim3(16, 32), blk, 0, stream>>>(hp, xtb, Whhb, Wihb, bih, bhh, cb, hn);
        head_gemm<<<dim3(256), blk, 0, stream>>>(hn, Wpb, bp, xtb, out + t * 16, 512);
    }
}

// Round 5
// 1121.137 us; speedup vs baseline: 1.0482x; 1.0482x over previous
//
#include <hip/hip_runtime.h>
#include <hip/hip_bf16.h>

typedef __bf16 bf16;
typedef bf16 bf16x8 __attribute__((ext_vector_type(8)));
typedef float f32x4 __attribute__((ext_vector_type(4)));

__device__ __forceinline__ void glds16(const void* g, void* l) {
    __builtin_amdgcn_global_load_lds(
        (const __attribute__((address_space(1))) void*)g,
        (__attribute__((address_space(3))) void*)l, 16, 0, 0);
}

__device__ __forceinline__ float sigm(float x) { return 1.0f / (1.0f + __expf(-x)); }
__device__ __forceinline__ float tanh_f(float x) { return 2.0f / (1.0f + __expf(-2.0f * x)) - 1.0f; }

// ---------------------------------------------------------------------------
// fp32 -> bf16 conversion of x + 11 matrices into one packed ws area.
// ---------------------------------------------------------------------------
struct Cvt11 { const float* src[11]; unsigned gcnt[11]; };  // gcnt = elems/8

__global__ __launch_bounds__(256) void cvt_all(Cvt11 a, bf16* __restrict__ dst,
                                               unsigned total_g) {
    unsigned g = blockIdx.x * 256 + threadIdx.x;
    if (g >= total_g) return;
    unsigned s = 0, base = 0;
    while (g >= base + a.gcnt[s]) { base += a.gcnt[s]; ++s; }
    const float* sp = a.src[s] + (size_t)(g - base) * 8;
    float4 v0 = ((const float4*)sp)[0];
    float4 v1 = ((const float4*)sp)[1];
    bf16x8 o;
    o[0] = (bf16)v0.x; o[1] = (bf16)v0.y; o[2] = (bf16)v0.z; o[3] = (bf16)v0.w;
    o[4] = (bf16)v1.x; o[5] = (bf16)v1.y; o[6] = (bf16)v1.z; o[7] = (bf16)v1.w;
    *(bf16x8*)(dst + (size_t)g * 8) = o;
}

// Pack Wcomb[2048,544] = Whh[2048,512] || Wih[2048,16] || zeros[16], bf16.
__global__ __launch_bounds__(128) void pack_w(const float* __restrict__ Whh,
                                              const float* __restrict__ Wih,
                                              bf16* __restrict__ Wc) {
    int row = blockIdx.x, seg = threadIdx.x;
    if (seg >= 68) return;
    bf16x8 o = {};
    if (seg < 64) {
        const float* sp = Whh + (size_t)row * 512 + seg * 8;
        float4 v0 = ((const float4*)sp)[0];
        float4 v1 = ((const float4*)sp)[1];
        o[0]=(bf16)v0.x; o[1]=(bf16)v0.y; o[2]=(bf16)v0.z; o[3]=(bf16)v0.w;
        o[4]=(bf16)v1.x; o[5]=(bf16)v1.y; o[6]=(bf16)v1.z; o[7]=(bf16)v1.w;
    } else if (seg < 66) {
        const float* sp = Wih + (size_t)row * 16 + (seg - 64) * 8;
        float4 v0 = ((const float4*)sp)[0];
        float4 v1 = ((const float4*)sp)[1];
        o[0]=(bf16)v0.x; o[1]=(bf16)v0.y; o[2]=(bf16)v0.z; o[3]=(bf16)v0.w;
        o[4]=(bf16)v1.x; o[5]=(bf16)v1.y; o[6]=(bf16)v1.z; o[7]=(bf16)v1.w;
    }
    *(bf16x8*)(Wc + (size_t)row * 544 + seg * 8) = o;
}

// Zero pad cols 528..543 of both h buffers.
__global__ __launch_bounds__(256) void zero_pad(bf16* __restrict__ h0,
                                                bf16* __restrict__ h1) {
    int g = blockIdx.x * 256 + threadIdx.x;  // 4096*2*2 = 16384
    int row = g >> 2, b = (g >> 1) & 1, half = g & 1;
    bf16* p = (b ? h1 : h0) + (size_t)row * 544 + 528 + half * 8;
    *(bf16x8*)p = (bf16x8){};
}

// ---------------------------------------------------------------------------
// GEMM: C[M,N](ldc) = act(A[M,K] @ W[N,K]^T + bias).  BM=64, BN=128, BK=32.
// glds16 async staging (m97 pattern).
// ---------------------------------------------------------------------------
template <int ACT, typename OutT>
__global__ __launch_bounds__(256) void gemm_bt(
    const bf16* __restrict__ A, const bf16* __restrict__ W,
    const float* __restrict__ bias, OutT* __restrict__ C,
    int M, int N, int K, int ldc)
{
    __shared__ __attribute__((aligned(16))) bf16 sA[64 * 32];   // 4 KB
    __shared__ __attribute__((aligned(16))) bf16 sB[128 * 32];  // 8 KB
    const int t = threadIdx.x;
    const int lane = t & 63, w = t >> 6;
    const int wm = w >> 1, wn = w & 1;
    const int quad = lane >> 4, l16 = lane & 15;
    const int m0 = blockIdx.y * 64, n0 = blockIdx.x * 128;

    f32x4 acc[2][4] = {};

    const int nk = K >> 5;
    for (int kc = 0; kc < nk; ++kc) {
        const int k0 = kc << 5;
        if (kc) __syncthreads();
        {   // A: 64x32 = 4 KB, dest elem = t*8 = row*32+kof
            int row = t >> 2, kof = (t & 3) << 3;
            glds16(A + (size_t)(m0 + row) * K + k0 + kof, (char*)sA + (w << 10));
        }
        for (int i = 0; i < 2; ++i) {  // B: 128x32 = 8 KB
            int gi = (i << 8) + t;
            int row = gi >> 2, kof = (gi & 3) << 3;
            glds16(W + (size_t)(n0 + row) * K + k0 + kof,
                   (char*)sB + (i << 12) + (w << 10));
        }
        __syncthreads();
        bf16x8 af[2], bfr[4];
        for (int mi = 0; mi < 2; ++mi)
            af[mi] = *(const bf16x8*)(sA + ((wm * 32 + mi * 16 + l16) * 32 + quad * 8));
        for (int ni = 0; ni < 4; ++ni)
            bfr[ni] = *(const bf16x8*)(sB + ((wn * 64 + ni * 16 + l16) * 32 + quad * 8));
        for (int mi = 0; mi < 2; ++mi)
            for (int ni = 0; ni < 4; ++ni)
                acc[mi][ni] = __builtin_amdgcn_mfma_f32_16x16x32_bf16(
                    af[mi], bfr[ni], acc[mi][ni], 0, 0, 0);
    }
    for (int mi = 0; mi < 2; ++mi) {
        for (int ni = 0; ni < 4; ++ni) {
            int gn = n0 + wn * 64 + ni * 16 + l16;
            float bv = bias[gn];
            for (int r = 0; r < 4; ++r) {
                int gm = m0 + wm * 32 + mi * 16 + quad * 4 + r;
                float v = acc[mi][ni][r] + bv;
                if (ACT) v = v >= 0.f ? v : 0.2f * v;
                C[(size_t)gm * ldc + gn] = (OutT)v;
            }
        }
    }
}

// ---------------------------------------------------------------------------
// Fused LSTM step on packed layout: hin[4096,544] = h||xt||0,
// Wc[2048,544] = Whh||Wih||0.  17 clean BK=32 iterations, glds16 staging.
// Block: 128 rows x 32 units x 4 gates; lane owns all 4 gates of (row,unit).
// ---------------------------------------------------------------------------
__global__ __launch_bounds__(256) void lstm_step(
    const bf16* __restrict__ hin, const bf16* __restrict__ Wc,
    const float* __restrict__ bih, const float* __restrict__ bhh,
    float* __restrict__ cbuf, bf16* __restrict__ hout)
{
    __shared__ __attribute__((aligned(16))) bf16 sA[128 * 32];  // 8 KB
    __shared__ __attribute__((aligned(16))) bf16 sB[128 * 32];  // 8 KB
    const int t = threadIdx.x;
    const int lane = t & 63, w = t >> 6;
    const int wm = w >> 1, wn = w & 1;
    const int quad = lane >> 4, l16 = lane & 15;
    const int m0 = blockIdx.y * 128;
    const int j0 = blockIdx.x * 32;

    f32x4 acc[4][4] = {};  // [mi][gate]

    for (int kc = 0; kc < 17; ++kc) {
        const int k0 = kc << 5;
        if (kc) __syncthreads();
        for (int i = 0; i < 2; ++i) {  // A tile: 128 rows of h (stride 544)
            int gi = (i << 8) + t;
            int row = gi >> 2, kof = (gi & 3) << 3;
            glds16(hin + (size_t)(m0 + row) * 544 + k0 + kof,
                   (char*)sA + (i << 12) + (w << 10));
        }
        for (int i = 0; i < 2; ++i) {  // B tile: 4 gates x 32 units
            int gi = (i << 8) + t;
            int row = gi >> 2, kof = (gi & 3) << 3;
            int wr = ((row >> 5) << 9) + j0 + (row & 31);  // gate*512 + j0 + jj
            glds16(Wc + (size_t)wr * 544 + k0 + kof,
                   (char*)sB + (i << 12) + (w << 10));
        }
        __syncthreads();
        bf16x8 af[4], bfr[4];
        for (int mi = 0; mi < 4; ++mi)
            af[mi] = *(const bf16x8*)(sA + ((wm * 64 + mi * 16 + l16) * 32 + quad * 8));
        for (int g = 0; g < 4; ++g)
            bfr[g] = *(const bf16x8*)(sB + ((g * 32 + wn * 16 + l16) * 32 + quad * 8));
        for (int mi = 0; mi < 4; ++mi)
            for (int g = 0; g < 4; ++g)
                acc[mi][g] = __builtin_amdgcn_mfma_f32_16x16x32_bf16(
                    af[mi], bfr[g], acc[mi][g], 0, 0, 0);
    }

    // epilogue: gate nonlinearities + c/h update (c fp32, stride 512)
    const int j = j0 + wn * 16 + l16;
    float bsum[4];
    for (int g = 0; g < 4; ++g)
        bsum[g] = bih[(g << 9) + j] + bhh[(g << 9) + j];
    for (int mi = 0; mi < 4; ++mi) {
        for (int r = 0; r < 4; ++r) {
            int gm = m0 + wm * 64 + mi * 16 + quad * 4 + r;
            float i_ = sigm(acc[mi][0][r] + bsum[0]);
            float f_ = sigm(acc[mi][1][r] + bsum[1]);
            float g_ = tanh_f(acc[mi][2][r] + bsum[2]);
            float o_ = sigm(acc[mi][3][r] + bsum[3]);
            float cn = f_ * cbuf[(size_t)gm * 512 + j] + i_ * g_;
            cbuf[(size_t)gm * 512 + j] = cn;
            hout[(size_t)gm * 544 + j] = (bf16)(o_ * tanh_f(cn));
        }
    }
}

// ---------------------------------------------------------------------------
// MFMA head: p = A[:,0:512](lda) @ Wp[16,512]^T + b; out = [softmax(p[:,:15]),
// sigmoid(p[:,15])].  64 blocks x 4 waves; wave = 16 rows, no LDS.
// Writes bf16 xt into packed h-buffer cols and optional fp32 final output.
// ---------------------------------------------------------------------------
__global__ __launch_bounds__(256) void head_mfma(
    const bf16* __restrict__ A, int lda,
    const bf16* __restrict__ Wp16,
    const float* __restrict__ bias,
    bf16* __restrict__ xt_dst, int ldx,
    float* __restrict__ outp, int ldo)
{
    const int t = threadIdx.x;
    const int lane = t & 63, w = t >> 6;
    const int quad = lane >> 4, l16 = lane & 15;
    const int r0 = blockIdx.x * 64 + w * 16;
    f32x4 acc = {};
    for (int kk = 0; kk < 16; ++kk) {
        bf16x8 a = *(const bf16x8*)(A + (size_t)(r0 + l16) * lda + kk * 32 + quad * 8);
        bf16x8 b = *(const bf16x8*)(Wp16 + (size_t)l16 * 512 + kk * 32 + quad * 8);
        acc = __builtin_amdgcn_mfma_f32_16x16x32_bf16(a, b, acc, 0, 0, 0);
    }
    const int n = l16;
    const float bv = bias[n];
    for (int r = 0; r < 4; ++r) {
        float p = acc[r] + bv;
        float vmax = (n == 15) ? -3.0e38f : p;
        for (int m = 1; m < 16; m <<= 1) vmax = fmaxf(vmax, __shfl_xor(vmax, m));
        float e = (n == 15) ? 0.f : __expf(p - vmax);
        float s = e;
        for (int m = 1; m < 16; m <<= 1) s += __shfl_xor(s, m);
        float res = (n == 15) ? sigm(p) : e / s;
        int gr = r0 + quad * 4 + r;
        xt_dst[(size_t)gr * ldx + n] = (bf16)res;
        if (outp) outp[(size_t)gr * ldo + n] = res;
    }
}

// ---------------------------------------------------------------------------
extern "C" void kernel_launch(void* const* d_in, const int* in_sizes, int n_in,
                              void* d_out, int out_size, void* d_ws, size_t ws_size,
                              hipStream_t stream) {
    const float* xf   = (const float*)d_in[0];
    const float* W1f  = (const float*)d_in[1];  const float* b1  = (const float*)d_in[2];
    const float* W2f  = (const float*)d_in[3];  const float* b2  = (const float*)d_in[4];
    const float* W3f  = (const float*)d_in[5];  const float* b3  = (const float*)d_in[6];
    const float* Wh1f = (const float*)d_in[7];  const float* bh1 = (const float*)d_in[8];
    const float* Wh2f = (const float*)d_in[9];  const float* bh2 = (const float*)d_in[10];
    const float* Wc1f = (const float*)d_in[11]; const float* bc1 = (const float*)d_in[12];
    const float* Wc2f = (const float*)d_in[13]; const float* bc2 = (const float*)d_in[14];
    const float* Wx1f = (const float*)d_in[15]; const float* bx1 = (const float*)d_in[16];
    const float* Wx2f = (const float*)d_in[17]; const float* bx2 = (const float*)d_in[18];
    const float* Wihf = (const float*)d_in[19]; const float* bih = (const float*)d_in[20];
    const float* Whhf = (const float*)d_in[21]; const float* bhh = (const float*)d_in[22];
    const float* Wpf  = (const float*)d_in[23]; const float* bp  = (const float*)d_in[24];
    float* out = (float*)d_out;
    char* ws = (char*)d_ws;

    // layout (bytes): h1b/bufA 0..4456448 | bufB ..8650752 | h0b ..13107200 |
    // cb ..21495808 | Wcomb ..23724032 | cvt ..28606464  (~27.3 MB)
    bf16*  h1b  = (bf16*)(ws + 0);            // [4096,544]; early: z-buf (ldc 512)
    bf16*  bufA = h1b;                        //   alias — z3 dead before step 0
    bf16*  bufB = (bf16*)(ws + 4456448);      // [4096,512]
    bf16*  h0b  = (bf16*)(ws + 8650752);      // [4096,544]
    float* cb   = (float*)(ws + 13107200);    // [4096,512] fp32
    bf16*  Wcb  = (bf16*)(ws + 21495808);     // [2048,544]
    bf16*  cvt  = (bf16*)(ws + 23724032);     // packed bf16 weights

    const unsigned Ns[11] = {
        4096u * 128u,  // x
        512u * 128u,   // W1
        512u * 512u, 512u * 512u, 512u * 512u, 512u * 512u,  // W2,W3,Wh1,Wh2
        512u * 512u, 512u * 512u, 512u * 512u,               // Wc1,Wc2,Wx1
        16u * 512u,    // Wx2
        16u * 512u     // Wp
    };
    const float* srcs[11] = { xf, W1f, W2f, W3f, Wh1f, Wh2f, Wc1f, Wc2f,
                              Wx1f, Wx2f, Wpf };
    Cvt11 ca;
    unsigned off[12]; off[0] = 0;
    for (int i = 0; i < 11; ++i) {
        ca.src[i] = srcs[i];
        ca.gcnt[i] = Ns[i] >> 3;
        off[i + 1] = off[i] + Ns[i];
    }
    unsigned total_g = off[11] >> 3;
    cvt_all<<<dim3((total_g + 255) / 256), dim3(256), 0, stream>>>(ca, cvt, total_g);
    pack_w<<<dim3(2048), dim3(128), 0, stream>>>(Whhf, Wihf, Wcb);

    const bf16* xb   = cvt + off[0];
    const bf16* W1b  = cvt + off[1];
    const bf16* W2b  = cvt + off[2];
    const bf16* W3b  = cvt + off[3];
    const bf16* Wh1b = cvt + off[4];
    const bf16* Wh2b = cvt + off[5];
    const bf16* Wc1b = cvt + off[6];
    const bf16* Wc2b = cvt + off[7];
    const bf16* Wx1b = cvt + off[8];
    const bf16* Wx2b = cvt + off[9];
    const bf16* Wpb  = cvt + off[10];

    dim3 blk(256);
    dim3 gg(4, 64);  // N/128 x M/64
    gemm_bt<1, bf16 ><<<gg, blk, 0, stream>>>(xb,   W1b,  b1,  bufA, 4096, 512, 128, 512);
    gemm_bt<1, bf16 ><<<gg, blk, 0, stream>>>(bufA, W2b,  b2,  bufB, 4096, 512, 512, 512);
    gemm_bt<1, bf16 ><<<gg, blk, 0, stream>>>(bufB, W3b,  b3,  bufA, 4096, 512, 512, 512);
    gemm_bt<1, bf16 ><<<gg, blk, 0, stream>>>(bufA, Wh1b, bh1, bufB, 4096, 512, 512, 512);
    gemm_bt<0, bf16 ><<<gg, blk, 0, stream>>>(bufB, Wh2b, bh2, h0b,  4096, 512, 512, 544);
    gemm_bt<1, bf16 ><<<gg, blk, 0, stream>>>(bufA, Wc1b, bc1, bufB, 4096, 512, 512, 512);
    gemm_bt<0, float><<<gg, blk, 0, stream>>>(bufB, Wc2b, bc2, cb,   4096, 512, 512, 512);
    gemm_bt<1, bf16 ><<<gg, blk, 0, stream>>>(bufA, Wx1b, bx1, bufB, 4096, 512, 512, 512);
    // bufA (=h1b) dead from here; zero pads before any h-buffer use
    zero_pad<<<dim3(64), blk, 0, stream>>>(h0b, h1b);
    head_mfma<<<dim3(64), blk, 0, stream>>>(bufB, 512, Wx2b, bx2,
                                            h0b + 512, 544, (float*)nullptr, 0);

    bf16* hb[2] = { h0b, h1b };
    for (int t = 0; t < 32; ++t) {
        const bf16* hp = hb[t & 1];
        bf16* hn = hb[(t + 1) & 1];
        lstm_step<<<dim3(16, 32), blk, 0, stream>>>(hp, Wcb, bih, bhh, cb, hn);
        head_mfma<<<dim3(64), blk, 0, stream>>>(hn, 544, Wpb, bp,
                                                hn + 512, 544, out + t * 16, 512);
    }
}